// Round 13
// baseline (382.141 us; speedup 1.0000x reference)
//
#include <hip/hip_runtime.h>

typedef unsigned short u16;
typedef unsigned int   u32;
typedef unsigned long long u64;
typedef __attribute__((ext_vector_type(4))) int   i32x4;
typedef __attribute__((ext_vector_type(4))) float f32x4;
typedef __attribute__((ext_vector_type(8))) short s16x8;

#define NROWS 98304L   // B*A
#define LDF   512      // feat row stride (250 h | 6 pad | 250 gat | 6 pad)

__device__ __forceinline__ u16 f2bf(float x) {
  union { float f; u32 u; } v; v.f = x;
  return (u16)((v.u + 0x7FFFu + ((v.u >> 16) & 1u)) >> 16);
}
__device__ __forceinline__ float bf2f(u16 b) {
  union { float f; u32 u; } v; v.u = ((u32)b) << 16;
  return v.f;
}

// async global->LDS, 16B per lane; LDS dest = wave-uniform base + lane*16 (m104)
__device__ __forceinline__ void gload_lds16(const u16* g, u16* l) {
  __builtin_amdgcn_global_load_lds(
      (const __attribute__((address_space(1))) unsigned int*)g,
      (__attribute__((address_space(3))) unsigned int*)l, 16, 0, 0);
}

// ---------------- weight prep: transpose + zero-pad to bf16 ----------------
// Wgat_t rows e=250/251 get u_l[h]=W_gat[h]@a_l[h], u_r[h] so the Wh GEMM
// emits el/er as free output columns (el = h . (W_gat @ a_l)).
__global__ __launch_bounds__(256)
void prep_weights(const float* __restrict__ W_emb, const float* __restrict__ b_emb,
                  const float* __restrict__ W_gat, const float* __restrict__ a_l,
                  const float* __restrict__ a_r, const float* __restrict__ W1,
                  const float* __restrict__ b1, const float* __restrict__ V1,
                  const float* __restrict__ vb1,
                  u16* __restrict__ Wemb_t, u16* __restrict__ Wgat_t,
                  u16* __restrict__ W1V1_t, float* __restrict__ bembp,
                  float* __restrict__ b1vb1)
{
  const int idx = blockIdx.x * 256 + threadIdx.x;
  const int stride = gridDim.x * 256;
  // Wemb_t[n][k], n<256 (pad 250..255), k<128
  for (int t = idx; t < 256 * 128; t += stride) {
    int n = t >> 7, k = t & 127;
    Wemb_t[t] = f2bf(n < 250 ? W_emb[k * 250 + n] : 0.f);
  }
  // Wgat_t[h][e][d] = W_gat[h][d][e] (256x256 padded); rows 250/251 = u_l/u_r
  for (int t = idx; t < 3 * 256 * 256; t += stride) {
    int h = t >> 16, rem = t & 65535, e = rem >> 8, d = rem & 255;
    float v = 0.f;
    if (e < 250 && d < 250) {
      v = W_gat[(h * 250 + d) * 250 + e];
    } else if ((e == 250 || e == 251) && d < 250) {
      const float* av = ((e == 250) ? a_l : a_r) + h * 250;
      const float* wrow = W_gat + ((long)h * 250 + d) * 250;
      float s = 0.f;
      for (int q = 0; q < 250; q++) s += wrow[q] * av[q];
      v = s;
    }
    Wgat_t[t] = f2bf(v);
  }
  // W1V1_t[n][k]: n<256 actor col, else critic col; k maps feat-pad rows
  for (int t = idx; t < 512 * 512; t += stride) {
    int n = t >> 9, k = t & 511;
    const float* src = (n < 256) ? W1 : V1;
    int col = n & 255;
    float v = 0.f;
    if (k < 250) v = src[k * 256 + col];
    else if (k >= 256 && k < 506) v = src[(k - 6) * 256 + col];
    W1V1_t[t] = f2bf(v);
  }
  for (int t = idx; t < 512; t += stride) b1vb1[t] = (t < 256) ? b1[t] : vb1[t - 256];
  for (int t = idx; t < 256; t += stride) bembp[t] = (t < 250) ? b_emb[t] : 0.f;
}

// ---------------- gemm1f: fused x(fp32)->bf16 + embed GEMM ----------------
__global__ __launch_bounds__(256, 2)
void gemm1f(const float* __restrict__ X,          // [NROWS][128] fp32
            const u16* __restrict__ B,            // Wemb_t [256][128]
            u16* __restrict__ C,                  // feat, ldc=512
            const float* __restrict__ bias)       // bembp [256]
{
  __shared__ __align__(16) u16 At[128 * 64];
  __shared__ __align__(16) u16 Bt[128 * 64];
  const int tid = threadIdx.x;
  const int w = tid >> 6, lane = tid & 63;
  const int fl = lane & 15, fh = lane >> 4;
  const int wr = (w >> 1) * 64, wc = (w & 1) * 64;
  const int srow = lane >> 3;                    // 0..7
  const int slot = lane & 7;                     // 0..7
  const int schunk = ((slot ^ srow) << 3);       // source chunk (elems)
  const int swz = (fl & 7) << 3;

  const int nidx = blockIdx.x;                   // 0..1
  const int midx = blockIdx.y;                   // 0..767

  const float* Ax = X + (long)midx * 128 * 128;
  const u16* Bb = B + nidx * 128 * 128;
  u16* Cb = C + (long)midx * 128 * LDF + nidx * 128;
  const float* biasb = bias + nidx * 128;

  f32x4 acc[4][4];
  #pragma unroll
  for (int m = 0; m < 4; m++)
    #pragma unroll
    for (int n = 0; n < 4; n++)
      acc[m][n] = f32x4{0.f, 0.f, 0.f, 0.f};

  for (int ks = 0; ks < 2; ks++) {
    __syncthreads();
    #pragma unroll
    for (int c = 0; c < 4; c++) {
      const int row = w * 32 + c * 8 + srow;
      gload_lds16(Bb + (long)row * 128 + ks * 64 + schunk, Bt + (w * 4 + c) * 512);
      const float* src = Ax + (long)row * 128 + ks * 64 + schunk;
      f32x4 lo = *(const f32x4*)src;
      f32x4 hi = *(const f32x4*)(src + 4);
      i32x4 o;
      o[0] = (int)((u32)f2bf(lo[0]) | ((u32)f2bf(lo[1]) << 16));
      o[1] = (int)((u32)f2bf(lo[2]) | ((u32)f2bf(lo[3]) << 16));
      o[2] = (int)((u32)f2bf(hi[0]) | ((u32)f2bf(hi[1]) << 16));
      o[3] = (int)((u32)f2bf(hi[2]) | ((u32)f2bf(hi[3]) << 16));
      *(i32x4*)(At + row * 64 + slot * 8) = o;
    }
    __syncthreads();
    #pragma unroll
    for (int kk = 0; kk < 2; kk++) {
      s16x8 af[4], bfr[4];
      #pragma unroll
      for (int m = 0; m < 4; m++)
        af[m] = *(const s16x8*)(At + (wr + m * 16 + fl) * 64 + ((kk * 32 + fh * 8) ^ swz));
      #pragma unroll
      for (int n = 0; n < 4; n++)
        bfr[n] = *(const s16x8*)(Bt + (wc + n * 16 + fl) * 64 + ((kk * 32 + fh * 8) ^ swz));
      #pragma unroll
      for (int m = 0; m < 4; m++)
        #pragma unroll
        for (int n = 0; n < 4; n++)
          acc[m][n] = __builtin_amdgcn_mfma_f32_16x16x32_bf16(af[m], bfr[n], acc[m][n], 0, 0, 0);
    }
  }
  #pragma unroll
  for (int m = 0; m < 4; m++) {
    const int r0 = wr + m * 16 + fh * 4;
    #pragma unroll
    for (int n = 0; n < 4; n++) {
      const int col = wc + n * 16 + fl;
      const float bvv = biasb[col];
      f32x4 v = acc[m][n];
      #pragma unroll
      for (int r = 0; r < 4; r++)
        Cb[(long)(r0 + r) * LDF + col] = f2bf(fmaxf(v[r] + bvv, 0.f));
    }
  }
}

// ---------------- gat_fused: Wh GEMM + in-LDS GAT attention ----------------
// BM=48 rows = 8 whole graphs per block; 512 threads = 8 waves, each wave
// computes 48x32 of the 256-wide Wh tile. Per head: 4-K-step GEMM (proven
// 2-barrier loop) -> Wh tile to swizzled LDS stash -> per-graph attention
// (el/er = stash cols 250/251, folded-weight trick) -> gacc += attn @ stash.
// Whb (151 MB HBM round trip) and the attn_gat kernel are eliminated.
__global__ __launch_bounds__(512, 4)
void gat_fused(const u16* __restrict__ feat_in,   // feat cols 0..255 = h
               const u16* __restrict__ Wg,        // Wgat_t [3][256][256]
               u16* __restrict__ feat_out)        // feat cols 256..511 = gat
{
  __shared__ __align__(16) u16 At[48 * 64];
  __shared__ __align__(16) u16 Bt[256 * 64];
  __shared__ __align__(16) u16 stash[48 * 256];   // Wh, swizzled chunks
  const int tid = threadIdx.x;
  const int w = tid >> 6, lane = tid & 63;
  const int fl = lane & 15, fh = lane >> 4;
  const int wc = w * 32;                          // wave's 32 output cols
  const int srow = lane >> 3;
  const int slot = lane & 7;
  const int schunk = ((slot ^ srow) << 3);
  const int swz = (fl & 7) << 3;

  const long rowbase = (long)blockIdx.x * 48;
  const u16* Ab = feat_in + rowbase * LDF;        // lda=512, K-cols 0..255

  const int g = tid >> 6;                         // graph 0..7 (== w)
  const int c0 = (lane) * 4;                      // 4 cols per thread, 0..252

  float gacc[6][4];
  #pragma unroll
  for (int i = 0; i < 6; i++)
    #pragma unroll
    for (int q = 0; q < 4; q++) gacc[i][q] = 0.f;

  for (int h = 0; h < 3; h++) {
    const u16* Bb = Wg + h * 65536;
    f32x4 acc[3][2];
    #pragma unroll
    for (int m = 0; m < 3; m++)
      #pragma unroll
      for (int n = 0; n < 2; n++) acc[m][n] = f32x4{0.f, 0.f, 0.f, 0.f};

    for (int ks = 0; ks < 4; ks++) {
      __syncthreads();
      #pragma unroll
      for (int s = 0; s < 4; s++) {               // B: 256x64 in 4 sweeps
        const int row = s * 64 + w * 8 + srow;
        gload_lds16(Bb + (long)row * 256 + ks * 64 + schunk, Bt + (s * 64 + w * 8) * 64);
      }
      if (w < 6) {                                // A: 48x64 by waves 0..5
        const int row = w * 8 + srow;
        gload_lds16(Ab + (long)row * LDF + ks * 64 + schunk, At + (w * 8) * 64);
      }
      __syncthreads();
      #pragma unroll
      for (int kk = 0; kk < 2; kk++) {
        s16x8 af[3], bfr[2];
        #pragma unroll
        for (int m = 0; m < 3; m++)
          af[m] = *(const s16x8*)(At + (m * 16 + fl) * 64 + ((kk * 32 + fh * 8) ^ swz));
        #pragma unroll
        for (int n = 0; n < 2; n++)
          bfr[n] = *(const s16x8*)(Bt + (wc + n * 16 + fl) * 64 + ((kk * 32 + fh * 8) ^ swz));
        #pragma unroll
        for (int m = 0; m < 3; m++)
          #pragma unroll
          for (int n = 0; n < 2; n++)
            acc[m][n] = __builtin_amdgcn_mfma_f32_16x16x32_bf16(af[m], bfr[n], acc[m][n], 0, 0, 0);
      }
    }
    // acc -> stash (bf16, byte = row*512 + ((col*2) ^ ((row&7)<<4)))
    #pragma unroll
    for (int m = 0; m < 3; m++)
      #pragma unroll
      for (int n = 0; n < 2; n++)
        #pragma unroll
        for (int r = 0; r < 4; r++) {
          const int row = m * 16 + fh * 4 + r;
          const int col = wc + n * 16 + fl;
          const int byte = row * 512 + ((col * 2) ^ ((row & 7) << 4));
          *(u16*)((char*)stash + byte) = f2bf(acc[m][n][r]);
        }
    __syncthreads();

    // ---- attention for this head (redundant across the graph's 64 lanes) --
    float el[6], er[6], mx[6], inv[6];
    #pragma unroll
    for (int i = 0; i < 6; i++) {
      const int row = g * 6 + i;
      const int byte = row * 512 + (500 ^ ((row & 7) << 4));   // cols 250/251
      const u32 v = *(const u32*)((const char*)stash + byte);
      el[i] = bf2f((u16)v); er[i] = bf2f((u16)(v >> 16));
    }
    #pragma unroll
    for (int i = 0; i < 6; i++) {
      float m2 = -1e30f;
      #pragma unroll
      for (int j = 0; j < 6; j++) {
        float t = el[i] + er[j];
        t = (t > 0.f) ? t : 0.2f * t;
        m2 = fmaxf(m2, t);
      }
      float s = 0.f;
      #pragma unroll
      for (int j = 0; j < 6; j++) {
        float t = el[i] + er[j];
        t = (t > 0.f) ? t : 0.2f * t;
        s += __expf(t - m2);
      }
      mx[i] = m2; inv[i] = 1.f / s;
    }
    #pragma unroll
    for (int j = 0; j < 6; j++) {
      const int row = g * 6 + j;
      const int byte = row * 512 + ((c0 * 2) ^ ((row & 7) << 4));
      const u64 v = *(const u64*)((const char*)stash + byte);
      float vj[4];
      vj[0] = bf2f((u16)v);         vj[1] = bf2f((u16)(v >> 16));
      vj[2] = bf2f((u16)(v >> 32)); vj[3] = bf2f((u16)(v >> 48));
      const float erj = er[j];
      #pragma unroll
      for (int i = 0; i < 6; i++) {
        float t = el[i] + erj;
        t = (t > 0.f) ? t : 0.2f * t;
        const float a = __expf(t - mx[i]) * inv[i];
        #pragma unroll
        for (int q = 0; q < 4; q++) gacc[i][q] += a * vj[q];
      }
    }
    __syncthreads();   // attn reads done before next head re-stages stash
  }

  // gat = gacc/3 -> feat cols 256..511
  const float k3 = 1.f / 3.f;
  #pragma unroll
  for (int i = 0; i < 6; i++) {
    u64 o = (u64)f2bf(gacc[i][0] * k3)
          | ((u64)f2bf(gacc[i][1] * k3) << 16)
          | ((u64)f2bf(gacc[i][2] * k3) << 32)
          | ((u64)f2bf(gacc[i][3] * k3) << 48);
    *(u64*)(feat_out + (rowbase + g * 6 + i) * LDF + 256 + c0) = o;
  }
}

// ---------------- gemm3p: feat @ [W1|V1] with partial-heads epilogue -------
// Single-buffered 128x128 GEMM; launch_bounds(256,4) caps total regs at 128
// (64 acc AGPR + <=64 arch) -> 4 waves/SIMD (r9: VGPR=64, Occ 39%, 87us).
// Grid (768,4) m-fast, sharers SPREAD in time [r7/r9/r11 evidence].
__global__ __launch_bounds__(256, 4)
void gemm3p(const u16* __restrict__ A,            // feat [NROWS][512]
            const u16* __restrict__ B,            // W1V1_t [512][512]
            const float* __restrict__ b1vb1,      // [512]
            const float* __restrict__ W2,         // [256][5]
            const float* __restrict__ V2,         // [256]
            float* __restrict__ partials)         // [4][NROWS][6]
{
  __shared__ __align__(16) u16 At[128 * 64];
  __shared__ __align__(16) u16 Bt[128 * 64];
  __shared__ float pstage[2][128][6];
  const int tid = threadIdx.x;
  const int w = tid >> 6, lane = tid & 63;
  const int fl = lane & 15, fh = lane >> 4;
  const int wr = (w >> 1) * 64, wc = (w & 1) * 64;
  const int wcid = w & 1;
  const int srow = lane >> 3;
  const int scol = (((lane & 7) ^ srow) << 3);
  const int swz = (fl & 7) << 3;

  const int midx = blockIdx.x;                   // 0..767
  const int nidx = blockIdx.y;                   // 0..3

  const u16* Ab = A + (long)midx * 128 * 512;
  const u16* Bb = B + (long)nidx * 128 * 512;

  f32x4 acc[4][4];
  #pragma unroll
  for (int m = 0; m < 4; m++)
    #pragma unroll
    for (int n = 0; n < 4; n++)
      acc[m][n] = f32x4{0.f, 0.f, 0.f, 0.f};

  for (int ks = 0; ks < 8; ks++) {
    __syncthreads();
    #pragma unroll
    for (int c = 0; c < 4; c++) {
      const int row = w * 32 + c * 8 + srow;
      gload_lds16(Ab + (long)row * 512 + ks * 64 + scol, At + (w * 4 + c) * 512);
      gload_lds16(Bb + (long)row * 512 + ks * 64 + scol, Bt + (w * 4 + c) * 512);
    }
    __syncthreads();
    #pragma unroll
    for (int kk = 0; kk < 2; kk++) {
      s16x8 af[4], bfr[4];
      #pragma unroll
      for (int m = 0; m < 4; m++)
        af[m] = *(const s16x8*)(At + (wr + m * 16 + fl) * 64 + ((kk * 32 + fh * 8) ^ swz));
      #pragma unroll
      for (int n = 0; n < 4; n++)
        bfr[n] = *(const s16x8*)(Bt + (wc + n * 16 + fl) * 64 + ((kk * 32 + fh * 8) ^ swz));
      #pragma unroll
      for (int m = 0; m < 4; m++)
        #pragma unroll
        for (int n = 0; n < 4; n++)
          acc[m][n] = __builtin_amdgcn_mfma_f32_16x16x32_bf16(af[m], bfr[n], acc[m][n], 0, 0, 0);
    }
  }

  // ---- partial-heads epilogue (register-lean) ----
  float bv[4];
  #pragma unroll
  for (int n = 0; n < 4; n++) bv[n] = b1vb1[nidx * 128 + wc + n * 16 + fl];

  #pragma unroll
  for (int m = 0; m < 4; m++) {
    float hidv[4][4];
    #pragma unroll
    for (int n = 0; n < 4; n++)
      #pragma unroll
      for (int r = 0; r < 4; r++)
        hidv[n][r] = fmaxf(acc[m][n][r] + bv[n], 0.f);
    const int row0 = wr + m * 16 + fh * 4;

    if (nidx < 2) {        // actor: hid cols nidx*128 + [0,128)
      #pragma unroll
      for (int j = 0; j < 5; j++) {
        float ps[4] = {0.f, 0.f, 0.f, 0.f};
        #pragma unroll
        for (int n = 0; n < 4; n++) {
          const float w2 = W2[(nidx * 128 + wc + n * 16 + fl) * 5 + j];
          #pragma unroll
          for (int r = 0; r < 4; r++) ps[r] += hidv[n][r] * w2;
        }
        #pragma unroll
        for (int off = 1; off < 16; off <<= 1)
          #pragma unroll
          for (int r = 0; r < 4; r++) ps[r] += __shfl_xor(ps[r], off, 16);
        if (fl == 0) {
          #pragma unroll
          for (int r = 0; r < 4; r++) pstage[wcid][row0 + r][j] = ps[r];
        }
      }
    } else {               // critic
      float ps[4] = {0.f, 0.f, 0.f, 0.f};
      #pragma unroll
      for (int n = 0; n < 4; n++) {
        const float v2c = V2[nidx * 128 + wc + n * 16 + fl - 256];
        #pragma unroll
        for (int r = 0; r < 4; r++) ps[r] += hidv[n][r] * v2c;
      }
      #pragma unroll
      for (int off = 1; off < 16; off <<= 1)
        #pragma unroll
        for (int r = 0; r < 4; r++) ps[r] += __shfl_xor(ps[r], off, 16);
      if (fl == 0) {
        #pragma unroll
        for (int r = 0; r < 4; r++) pstage[wcid][row0 + r][5] = ps[r];
      }
    }
  }
  __syncthreads();

  if (tid < 128) {
    float* dst = partials + ((long)nidx * NROWS + (long)midx * 128 + tid) * 6;
    if (nidx < 2) {
      #pragma unroll
      for (int j = 0; j < 5; j++)
        dst[j] = pstage[0][tid][j] + pstage[1][tid][j];
    } else {
      dst[5] = pstage[0][tid][5] + pstage[1][tid][5];
    }
  }
}

// ---------------- heads_final: sum partials, softmax | value ---------------
__global__ __launch_bounds__(256)
void heads_final(const float* __restrict__ partials, const float* __restrict__ b2,
                 const float* __restrict__ vb2, float* __restrict__ out)
{
  const long row = (long)blockIdx.x * 256 + threadIdx.x;
  const long slab = NROWS * 6;
  const float* p = partials + row * 6;
  float lg[5];
  #pragma unroll
  for (int j = 0; j < 5; j++) lg[j] = p[j] + p[slab + j] + b2[j];
  const float val = p[2 * slab + 5] + p[3 * slab + 5] + vb2[0];
  float mx = -1e30f;
  #pragma unroll
  for (int j = 0; j < 5; j++) mx = fmaxf(mx, lg[j]);
  float s = 0.f, e[5];
  #pragma unroll
  for (int j = 0; j < 5; j++) { e[j] = __expf(lg[j] - mx); s += e[j]; }
  const float inv = 1.f / s;
  float* op = out + row * 6;
  #pragma unroll
  for (int j = 0; j < 5; j++) op[j] = e[j] * inv;
  op[5] = val;
}

// ---------------- launch ----------------
extern "C" void kernel_launch(void* const* d_in, const int* in_sizes, int n_in,
                              void* d_out, int out_size, void* d_ws, size_t ws_size,
                              hipStream_t stream)
{
  const float* x     = (const float*)d_in[0];
  const float* W_emb = (const float*)d_in[1];
  const float* b_emb = (const float*)d_in[2];
  const float* W_gat = (const float*)d_in[3];
  const float* a_l   = (const float*)d_in[4];
  const float* a_r   = (const float*)d_in[5];
  const float* W1    = (const float*)d_in[6];
  const float* b1    = (const float*)d_in[7];
  const float* W2    = (const float*)d_in[8];
  const float* b2    = (const float*)d_in[9];
  const float* V1    = (const float*)d_in[10];
  const float* vb1   = (const float*)d_in[11];
  const float* V2    = (const float*)d_in[12];
  const float* vb2   = (const float*)d_in[13];

  char* ws = (char*)d_ws;
  u16* feat = (u16*)ws;                       // [98304][512] bf16 = 100,663,296 B
  char* r2  = ws + 100663296L;
  float* partials = (float*)r2;               // [4][98304][6] fp32 = 9.4 MB
  char* wt  = r2 + 150994944L;
  u16*   Wemb_t = (u16*)wt;                   // 256*128
  u16*   Wgat_t = (u16*)(wt + 65536);         // 3*256*256
  u16*   W1V1_t = (u16*)(wt + 458752);        // 512*512
  float* b1vb1  = (float*)(wt + 983040);      // 512
  float* bembp  = (float*)(wt + 985088);      // 256

  prep_weights<<<256, 256, 0, stream>>>(W_emb, b_emb, W_gat, a_l, a_r, W1, b1, V1, vb1,
                                        Wemb_t, Wgat_t, W1V1_t, bembp, b1vb1);
  // h = relu(x @ W_emb + b) -> feat[:,0:256]  (fused fp32->bf16 conversion)
  gemm1f<<<dim3(2, 768), 256, 0, stream>>>(x, Wemb_t, feat, bembp);
  // Wh GEMM + in-LDS attention -> feat[:,256:512]  (Whb round trip removed)
  gat_fused<<<2048, 512, 0, stream>>>(feat, Wgat_t, feat);
  // hidden = relu(feat @ [W1|V1] + b) folded into per-block head partials
  gemm3p<<<dim3(768, 4), 256, 0, stream>>>(feat, W1V1_t, b1vb1, W2, V2, partials);
  // sum partials, softmax | value
  heads_final<<<384, 256, 0, stream>>>(partials, b2, vb2, (float*)d_out);
}